// Round 1
// baseline (2740.748 us; speedup 1.0000x reference)
//
#include <hip/hip_runtime.h>
#include <hip/hip_bf16.h>

// HeteroGraphEncoder: 3-layer hetero GraphSAGE + pool + MLP head. fp32 throughout.
// Sizes (from reference): NE=100000, NT=20000, EE=1e6, ET=5e5, TE=5e5, D=128, B=64, OUT=64, L=3.

#define D 128
#define NB 64
#define OUTD 64
#define NLAY 3

// ---------------- gather initial embeddings (ids are arange, but honor them) ---------
__global__ void gather_rows(const float* __restrict__ emb, const int* __restrict__ ids,
                            float* __restrict__ x, int n) {
    int idx = blockIdx.x * blockDim.x + threadIdx.x;   // over n*32 float4
    if (idx >= n * 32) return;
    int r = idx >> 5, v = idx & 31;
    ((float4*)x)[(size_t)r * 32 + v] = ((const float4*)emb)[(size_t)ids[r] * 32 + v];
}

// ---------------- CSR build ----------------
__global__ void hist_kernel(const int* __restrict__ dst, int* __restrict__ deg, int E) {
    int e = blockIdx.x * blockDim.x + threadIdx.x;
    if (e < E) atomicAdd(&deg[dst[e]], 1);
}

// single-block exclusive scan; writes off[0..n] and cur[0..n-1]=off[i]
__global__ void scan_excl(const int* __restrict__ deg, int* __restrict__ off,
                          int* __restrict__ cur, int n) {
    __shared__ int buf[1024];
    __shared__ int carry;
    if (threadIdx.x == 0) carry = 0;
    __syncthreads();
    for (int base = 0; base < n; base += 1024) {
        int i = base + threadIdx.x;
        int v = (i < n) ? deg[i] : 0;
        buf[threadIdx.x] = v;
        __syncthreads();
        for (int s = 1; s < 1024; s <<= 1) {
            int t = (threadIdx.x >= s) ? buf[threadIdx.x - s] : 0;
            __syncthreads();
            buf[threadIdx.x] += t;
            __syncthreads();
        }
        int excl = buf[threadIdx.x] - v + carry;
        if (i < n) { off[i] = excl; cur[i] = excl; }
        __syncthreads();
        if (threadIdx.x == 0) carry += buf[1023];
        __syncthreads();
    }
    if (threadIdx.x == 0) off[n] = carry;
}

__global__ void fill_adj(const int* __restrict__ src, const int* __restrict__ dst,
                         int* __restrict__ cur, int* __restrict__ adj, int E) {
    int e = blockIdx.x * blockDim.x + threadIdx.x;
    if (e < E) {
        int p = atomicAdd(&cur[dst[e]], 1);
        adj[p] = src[e];
    }
}

// ---------------- mean aggregation: one wave per destination row ----------------
__global__ void agg_mean(const float* __restrict__ xsrc, const int* __restrict__ off,
                         const int* __restrict__ adj, float* __restrict__ out, int ndst) {
    int wave = (blockIdx.x * blockDim.x + threadIdx.x) >> 6;
    int lane = threadIdx.x & 63;
    if (wave >= ndst) return;
    int s0 = off[wave], s1 = off[wave + 1];
    float ax = 0.f, ay = 0.f;
    for (int j = s0; j < s1; ++j) {
        int s = adj[j];
        float2 v = ((const float2*)(xsrc + (size_t)s * D))[lane];
        ax += v.x; ay += v.y;
    }
    float inv = 1.0f / fmaxf((float)(s1 - s0), 1.0f);
    ((float2*)(out + (size_t)wave * D))[lane] = make_float2(ax * inv, ay * inv);
}

// ---------------- bias init: C[r][c] = b0[c] (+ b1[c]) ----------------
__global__ void init_bias2(float* __restrict__ C, const float* __restrict__ b0,
                           const float* __restrict__ b1p, int M) {
    int idx = blockIdx.x * blockDim.x + threadIdx.x;
    if (idx < M * D) {
        int c = idx & (D - 1);
        float v = b0[c];
        if (b1p) v += b1p[c];
        C[idx] = v;
    }
}

// ---------------- WrS[l] = Wr[l,0] + Wr[l,2] ----------------
__global__ void sum_wr(const float* __restrict__ Wr, float* __restrict__ out) {
    int idx = blockIdx.x * blockDim.x + threadIdx.x;   // 3*16384
    if (idx < NLAY * D * D) {
        int l = idx / (D * D); int o = idx - l * D * D;
        out[idx] = Wr[(size_t)(l * 3 + 0) * D * D + o] + Wr[(size_t)(l * 3 + 2) * D * D + o];
    }
}

// ---------------- fp32 GEMM accumulate: C(MxD) += A(MxD) @ W(DxD)^T ----------------
// BM=64, BK=32, 256 threads, each thread 4 rows x 8 cols.
__global__ __launch_bounds__(256) void gemm_acc(const float* __restrict__ A,
                                                const float* __restrict__ W,
                                                float* __restrict__ C, int M) {
    __shared__ float As[64][33];    // [row][k_local]
    __shared__ float Ws[32][132];   // Wt tile: [k_local][n]
    int tid = threadIdx.x;
    int row0 = blockIdx.x * 64;
    int tr = tid >> 4, tc = tid & 15;
    int r0 = tr * 4, c0 = tc * 8;
    float acc[4][8] = {};
    for (int k0 = 0; k0 < D; k0 += 32) {
        // stage A tile 64x32 (512 float4, 2/thread)
        #pragma unroll
        for (int i = 0; i < 2; ++i) {
            int lin = tid + i * 256;
            int r = lin >> 3, c4 = lin & 7;
            float4 v = make_float4(0.f, 0.f, 0.f, 0.f);
            if (row0 + r < M) v = ((const float4*)A)[(size_t)(row0 + r) * 32 + (k0 >> 2) + c4];
            As[r][c4 * 4 + 0] = v.x; As[r][c4 * 4 + 1] = v.y;
            As[r][c4 * 4 + 2] = v.z; As[r][c4 * 4 + 3] = v.w;
        }
        // stage Wt tile: W[n][k0..k0+32) -> Ws[k][n]  (1024 float4, 4/thread)
        #pragma unroll
        for (int i = 0; i < 4; ++i) {
            int lin = tid + i * 256;
            int n = lin >> 3, c4 = lin & 7;
            float4 v = ((const float4*)W)[(size_t)n * 32 + (k0 >> 2) + c4];
            Ws[c4 * 4 + 0][n] = v.x; Ws[c4 * 4 + 1][n] = v.y;
            Ws[c4 * 4 + 2][n] = v.z; Ws[c4 * 4 + 3][n] = v.w;
        }
        __syncthreads();
        #pragma unroll 8
        for (int k = 0; k < 32; ++k) {
            float a0 = As[r0 + 0][k], a1 = As[r0 + 1][k], a2 = As[r0 + 2][k], a3 = As[r0 + 3][k];
            float w[8];
            #pragma unroll
            for (int j = 0; j < 8; ++j) w[j] = Ws[k][c0 + j];
            #pragma unroll
            for (int j = 0; j < 8; ++j) {
                acc[0][j] += a0 * w[j]; acc[1][j] += a1 * w[j];
                acc[2][j] += a2 * w[j]; acc[3][j] += a3 * w[j];
            }
        }
        __syncthreads();
    }
    #pragma unroll
    for (int i = 0; i < 4; ++i) {
        int r = row0 + r0 + i;
        if (r < M) {
            float* cp = C + (size_t)r * D + c0;
            #pragma unroll
            for (int j = 0; j < 8; ++j) cp[j] += acc[i][j];
        }
    }
}

// ---------------- pooling: batch ids are sorted; block=128 threads (one per col) ---
__global__ void pool_kernel(const float* __restrict__ x, const int* __restrict__ batch,
                            float* __restrict__ pooled, int n, int chunk) {
    int c = threadIdx.x;   // 0..127
    int r0 = blockIdx.x * chunk;
    int r1 = min(r0 + chunk, n);
    if (r0 >= r1) return;
    int cur = batch[r0];
    float acc = 0.f;
    for (int r = r0; r < r1; ++r) {
        int b = batch[r];
        if (b != cur) { atomicAdd(&pooled[cur * D + c], acc); acc = 0.f; cur = b; }
        acc += x[(size_t)r * D + c];
    }
    atomicAdd(&pooled[cur * D + c], acc);
}

// ---------------- head: relu(pooled @ W1^T + b1) @ W2^T + b2 ----------------
__global__ void head_kernel(const float* __restrict__ pooled, const float* __restrict__ W1,
                            const float* __restrict__ b1, const float* __restrict__ W2,
                            const float* __restrict__ b2, float* __restrict__ out) {
    __shared__ float p[D];
    __shared__ float h[D];
    int b = blockIdx.x, t = threadIdx.x;   // 128 threads
    p[t] = pooled[b * D + t];
    __syncthreads();
    float s = b1[t];
    const float* w = W1 + (size_t)t * D;
    #pragma unroll 4
    for (int k = 0; k < D; ++k) s += p[k] * w[k];
    h[t] = fmaxf(s, 0.f);
    __syncthreads();
    if (t < OUTD) {
        float s2 = b2[t];
        const float* w2 = W2 + (size_t)t * D;
        #pragma unroll 4
        for (int k = 0; k < D; ++k) s2 += h[k] * w2[k];
        out[b * OUTD + t] = s2;
    }
}

extern "C" void kernel_launch(void* const* d_in, const int* in_sizes, int n_in,
                              void* d_out, int out_size, void* d_ws, size_t ws_size,
                              hipStream_t stream) {
    const int* event_ids   = (const int*)d_in[0];
    const int* trace_ids   = (const int*)d_in[1];
    const int* e2e_src     = (const int*)d_in[2];
    const int* e2e_dst     = (const int*)d_in[3];
    const int* e2t_src     = (const int*)d_in[4];
    const int* e2t_dst     = (const int*)d_in[5];
    const int* t2e_src     = (const int*)d_in[6];
    const int* t2e_dst     = (const int*)d_in[7];
    const int* event_batch = (const int*)d_in[8];
    const int* trace_batch = (const int*)d_in[9];
    const float* emb_event = (const float*)d_in[10];
    const float* emb_trace = (const float*)d_in[11];
    const float* Wl        = (const float*)d_in[12];
    const float* bl        = (const float*)d_in[13];
    const float* Wr        = (const float*)d_in[14];
    const float* W1        = (const float*)d_in[15];
    const float* b1        = (const float*)d_in[16];
    const float* W2        = (const float*)d_in[17];
    const float* b2        = (const float*)d_in[18];

    const int NE = in_sizes[0];
    const int NT = in_sizes[1];
    const int EE = in_sizes[2];
    const int ET = in_sizes[4];
    const int TE = in_sizes[6];

    // ---- workspace carve-up ----
    size_t cur = 0;
    auto alloc = [&](size_t bytes) -> void* {
        cur = (cur + 255) & ~(size_t)255;
        void* p = (char*)d_ws + cur;
        cur += bytes;
        return p;
    };
    float* x_event  = (float*)alloc((size_t)NE * D * 4);
    float* x_trace  = (float*)alloc((size_t)NT * D * 4);
    float* n_event  = (float*)alloc((size_t)NE * D * 4);
    float* n_trace  = (float*)alloc((size_t)NT * D * 4);
    float* m_buf    = (float*)alloc((size_t)NE * D * 4);
    float* pooled   = (float*)alloc((size_t)NB * D * 4);
    float* WrS      = (float*)alloc((size_t)NLAY * D * D * 4);
    int* deg_ee = (int*)alloc((size_t)NE * 4);
    int* off_ee = (int*)alloc((size_t)(NE + 1) * 4);
    int* cur_ee = (int*)alloc((size_t)NE * 4);
    int* adj_ee = (int*)alloc((size_t)EE * 4);
    int* deg_et = (int*)alloc((size_t)NT * 4);
    int* off_et = (int*)alloc((size_t)(NT + 1) * 4);
    int* cur_et = (int*)alloc((size_t)NT * 4);
    int* adj_et = (int*)alloc((size_t)ET * 4);
    int* deg_te = (int*)alloc((size_t)NE * 4);
    int* off_te = (int*)alloc((size_t)(NE + 1) * 4);
    int* cur_te = (int*)alloc((size_t)NE * 4);
    int* adj_te = (int*)alloc((size_t)TE * 4);
    (void)ws_size; (void)n_in; (void)out_size;

    // ---- initial embeddings ----
    gather_rows<<<(NE * 32 + 255) / 256, 256, 0, stream>>>(emb_event, event_ids, x_event, NE);
    gather_rows<<<(NT * 32 + 255) / 256, 256, 0, stream>>>(emb_trace, trace_ids, x_trace, NT);

    // ---- CSR build (once; graph is static across layers) ----
    hipMemsetAsync(deg_ee, 0, (size_t)NE * 4, stream);
    hipMemsetAsync(deg_et, 0, (size_t)NT * 4, stream);
    hipMemsetAsync(deg_te, 0, (size_t)NE * 4, stream);
    hist_kernel<<<(EE + 255) / 256, 256, 0, stream>>>(e2e_dst, deg_ee, EE);
    hist_kernel<<<(ET + 255) / 256, 256, 0, stream>>>(e2t_dst, deg_et, ET);
    hist_kernel<<<(TE + 255) / 256, 256, 0, stream>>>(t2e_dst, deg_te, TE);
    scan_excl<<<1, 1024, 0, stream>>>(deg_ee, off_ee, cur_ee, NE);
    scan_excl<<<1, 1024, 0, stream>>>(deg_et, off_et, cur_et, NT);
    scan_excl<<<1, 1024, 0, stream>>>(deg_te, off_te, cur_te, NE);
    fill_adj<<<(EE + 255) / 256, 256, 0, stream>>>(e2e_src, e2e_dst, cur_ee, adj_ee, EE);
    fill_adj<<<(ET + 255) / 256, 256, 0, stream>>>(e2t_src, e2t_dst, cur_et, adj_et, ET);
    fill_adj<<<(TE + 255) / 256, 256, 0, stream>>>(t2e_src, t2e_dst, cur_te, adj_te, TE);

    // ---- WrS[l] = Wr[l,0] + Wr[l,2] ----
    sum_wr<<<(NLAY * D * D + 255) / 256, 256, 0, stream>>>(Wr, WrS);

    // ---- layers ----
    for (int l = 0; l < NLAY; ++l) {
        const float* Wl0 = Wl + (size_t)(l * 3 + 0) * D * D;
        const float* Wl1 = Wl + (size_t)(l * 3 + 1) * D * D;
        const float* Wl2 = Wl + (size_t)(l * 3 + 2) * D * D;
        const float* bl0 = bl + (size_t)(l * 3 + 0) * D;
        const float* bl1 = bl + (size_t)(l * 3 + 1) * D;
        const float* bl2 = bl + (size_t)(l * 3 + 2) * D;
        const float* Wr1 = Wr + (size_t)(l * 3 + 1) * D * D;
        const float* WrSl = WrS + (size_t)l * D * D;

        // event side
        init_bias2<<<((size_t)NE * D + 255) / 256, 256, 0, stream>>>(n_event, bl0, bl2, NE);
        agg_mean<<<(NE + 3) / 4, 256, 0, stream>>>(x_event, off_ee, adj_ee, m_buf, NE);
        gemm_acc<<<(NE + 63) / 64, 256, 0, stream>>>(m_buf, Wl0, n_event, NE);
        agg_mean<<<(NE + 3) / 4, 256, 0, stream>>>(x_trace, off_te, adj_te, m_buf, NE);
        gemm_acc<<<(NE + 63) / 64, 256, 0, stream>>>(m_buf, Wl2, n_event, NE);
        gemm_acc<<<(NE + 63) / 64, 256, 0, stream>>>(x_event, WrSl, n_event, NE);

        // trace side
        init_bias2<<<((size_t)NT * D + 255) / 256, 256, 0, stream>>>(n_trace, bl1, nullptr, NT);
        agg_mean<<<(NT + 3) / 4, 256, 0, stream>>>(x_event, off_et, adj_et, m_buf, NT);
        gemm_acc<<<(NT + 63) / 64, 256, 0, stream>>>(m_buf, Wl1, n_trace, NT);
        gemm_acc<<<(NT + 63) / 64, 256, 0, stream>>>(x_trace, Wr1, n_trace, NT);

        // swap
        float* t;
        t = x_event; x_event = n_event; n_event = t;
        t = x_trace; x_trace = n_trace; n_trace = t;
    }

    // ---- pooling ----
    hipMemsetAsync(pooled, 0, (size_t)NB * D * 4, stream);
    const int CHUNK = 1024;
    pool_kernel<<<(NE + CHUNK - 1) / CHUNK, D, 0, stream>>>(x_event, event_batch, pooled, NE, CHUNK);
    pool_kernel<<<(NT + CHUNK - 1) / CHUNK, D, 0, stream>>>(x_trace, trace_batch, pooled, NT, CHUNK);

    // ---- head ----
    head_kernel<<<NB, D, 0, stream>>>(pooled, W1, b1, W2, b2, (float*)d_out);
}

// Round 2
// 1486.170 us; speedup vs baseline: 1.8442x; 1.8442x over previous
//
#include <hip/hip_runtime.h>
#include <hip/hip_bf16.h>

// HeteroGraphEncoder: 3-layer hetero GraphSAGE + pool + MLP head.
// bf16 activations/weights (hi+lo compensated weights), fp32 accumulation everywhere.
// NE=100000, NT=20000, EE=1e6, ET=5e5, TE=5e5, D=128, B=64, OUT=64, L=3.

#define D 128
#define NB 64
#define OUTD 64
#define NLAY 3

typedef __bf16 bf16;
typedef __bf16 bf16x2 __attribute__((ext_vector_type(2)));
typedef __bf16 bf16x8 __attribute__((ext_vector_type(8)));
typedef float  f32x16 __attribute__((ext_vector_type(16)));

// ---------------- initial embedding gather + cvt to bf16 ----------------
__global__ void gather_to_bf16(const float* __restrict__ emb, const int* __restrict__ ids,
                               bf16* __restrict__ x, int n) {
    int idx = blockIdx.x * blockDim.x + threadIdx.x;
    if (idx >= n * D) return;
    int r = idx >> 7;
    int c = idx & (D - 1);
    x[idx] = (bf16)emb[(size_t)ids[r] * D + c];
}

// ---------------- CSR build ----------------
__global__ void hist_kernel(const int* __restrict__ dst, int* __restrict__ deg, int E) {
    int e = blockIdx.x * blockDim.x + threadIdx.x;
    if (e < E) atomicAdd(&deg[dst[e]], 1);
}

// 3-phase scan: phase1 scans 1024 elems/block, phase2 scans block sums, phase3 adds offsets
__global__ void scan_phase1(const int* __restrict__ deg, int* __restrict__ off,
                            int* __restrict__ bsum, int n) {
    __shared__ int s[256];
    int t = threadIdx.x;
    int base = blockIdx.x * 1024 + t * 4;
    int v[4];
    #pragma unroll
    for (int i = 0; i < 4; ++i) v[i] = (base + i < n) ? deg[base + i] : 0;
    int tot = v[0] + v[1] + v[2] + v[3];
    s[t] = tot;
    __syncthreads();
    for (int st = 1; st < 256; st <<= 1) {
        int x = (t >= st) ? s[t - st] : 0;
        __syncthreads();
        s[t] += x;
        __syncthreads();
    }
    int run = s[t] - tot;  // exclusive prefix of this thread within block
    #pragma unroll
    for (int i = 0; i < 4; ++i) {
        if (base + i < n) off[base + i] = run;
        run += v[i];
    }
    if (t == 255) bsum[blockIdx.x] = s[255];
}

__global__ void scan_phase2(int* __restrict__ bsum, int nb) {  // nb <= 256
    __shared__ int s[256];
    int t = threadIdx.x;
    int v = (t < nb) ? bsum[t] : 0;
    s[t] = v;
    __syncthreads();
    for (int st = 1; st < 256; st <<= 1) {
        int x = (t >= st) ? s[t - st] : 0;
        __syncthreads();
        s[t] += x;
        __syncthreads();
    }
    if (t < nb) bsum[t] = s[t] - v;   // exclusive
    if (t == 0) bsum[nb] = s[255];    // total
}

__global__ void scan_phase3(int* __restrict__ off, int* __restrict__ cur,
                            const int* __restrict__ bsum, int n) {
    int i = blockIdx.x * blockDim.x + threadIdx.x;
    if (i < n) {
        int o = off[i] + bsum[i >> 10];
        off[i] = o;
        cur[i] = o;
    }
    if (i == 0) off[n] = bsum[(n + 1023) >> 10];
}

__global__ void fill_adj(const int* __restrict__ src, const int* __restrict__ dst,
                         int* __restrict__ cur, int* __restrict__ adj, int E) {
    int e = blockIdx.x * blockDim.x + threadIdx.x;
    if (e < E) {
        int p = atomicAdd(&cur[dst[e]], 1);
        adj[p] = src[e];
    }
}

// ---------------- mean aggregation: one wave per destination row (bf16 in/out) -------
__global__ void agg_mean_bf16(const bf16* __restrict__ xsrc, const int* __restrict__ off,
                              const int* __restrict__ adj, bf16* __restrict__ out, int ndst) {
    int wave = (blockIdx.x * blockDim.x + threadIdx.x) >> 6;
    int lane = threadIdx.x & 63;
    if (wave >= ndst) return;
    int s0 = off[wave], s1 = off[wave + 1];
    float ax = 0.f, ay = 0.f;
    for (int j = s0; j < s1; ++j) {
        int s = adj[j];
        bf16x2 v = ((const bf16x2*)(xsrc + (size_t)s * D))[lane];
        ax += (float)v.x;
        ay += (float)v.y;
    }
    float inv = 1.0f / fmaxf((float)(s1 - s0), 1.0f);
    bf16x2 o;
    o.x = (bf16)(ax * inv);
    o.y = (bf16)(ay * inv);
    ((bf16x2*)(out + (size_t)wave * D))[lane] = o;
}

// ---------------- weight prep: split into bf16 hi/lo, fold Wr0+Wr2, biases ----------
// per-layer layout in wbuf (each matrix 128x128 bf16 = 16384 elems):
//   slot 0/1: Wl0 hi/lo   slot 2/3: Wl2 hi/lo   slot 4/5: (Wr0+Wr2) hi/lo
//   slot 6/7: Wl1 hi/lo   slot 8/9: Wr1 hi/lo
__global__ void prep_weights(const float* __restrict__ Wl, const float* __restrict__ Wr,
                             const float* __restrict__ bl, bf16* __restrict__ wbuf,
                             float* __restrict__ bbuf) {
    int idx = blockIdx.x * blockDim.x + threadIdx.x;  // over NLAY*16384
    if (idx >= NLAY * D * D) return;
    int l = idx / (D * D), o = idx - l * D * D;
    bf16* base = wbuf + (size_t)l * 10 * D * D;
    float w;
    bf16 h;
    w = Wl[(size_t)(l * 3 + 0) * D * D + o]; h = (bf16)w;
    base[0 * D * D + o] = h; base[1 * D * D + o] = (bf16)(w - (float)h);
    w = Wl[(size_t)(l * 3 + 2) * D * D + o]; h = (bf16)w;
    base[2 * D * D + o] = h; base[3 * D * D + o] = (bf16)(w - (float)h);
    w = Wr[(size_t)(l * 3 + 0) * D * D + o] + Wr[(size_t)(l * 3 + 2) * D * D + o]; h = (bf16)w;
    base[4 * D * D + o] = h; base[5 * D * D + o] = (bf16)(w - (float)h);
    w = Wl[(size_t)(l * 3 + 1) * D * D + o]; h = (bf16)w;
    base[6 * D * D + o] = h; base[7 * D * D + o] = (bf16)(w - (float)h);
    w = Wr[(size_t)(l * 3 + 1) * D * D + o]; h = (bf16)w;
    base[8 * D * D + o] = h; base[9 * D * D + o] = (bf16)(w - (float)h);
    if (o < D) {
        bbuf[l * 2 * D + o]     = bl[(size_t)(l * 3 + 0) * D + o] + bl[(size_t)(l * 3 + 2) * D + o];
        bbuf[l * 2 * D + D + o] = bl[(size_t)(l * 3 + 1) * D + o];
    }
}

// ---------------- fused MFMA GEMM: out = bias + sum_s A_s @ W_s^T (bf16 in, bf16 out) -
// 256 threads = 4 waves; wave handles 32 rows x 128 cols; K=128 in 8 steps of 16.
// W packed per matrix as [hi (16384)][lo (16384)] consecutively.
// mfma_f32_32x32x16_bf16: A[m=lane&31][k=(lane>>5)*8+j]; B[k][n=lane&31] = W[n][k];
// C/D: col=lane&31, row=(reg&3)+8*(reg>>2)+4*(lane>>5)  [measured: learn_hip m74/m101]
template<int NMAT>
__global__ __launch_bounds__(256) void gemm_fused(const bf16* __restrict__ A0,
                                                  const bf16* __restrict__ A1,
                                                  const bf16* __restrict__ A2,
                                                  const bf16* __restrict__ W,
                                                  const float* __restrict__ bias,
                                                  bf16* __restrict__ out, int M) {
    int wave = threadIdx.x >> 6, lane = threadIdx.x & 63;
    int row0 = blockIdx.x * 128 + wave * 32;
    int m = lane & 31, half = lane >> 5;
    int arow = min(row0 + m, M - 1);
    const bf16* a0 = A0 + (size_t)arow * D + half * 8;
    const bf16* a1 = (NMAT > 1) ? (A1 + (size_t)arow * D + half * 8) : nullptr;
    const bf16* a2 = (NMAT > 2) ? (A2 + (size_t)arow * D + half * 8) : nullptr;

    f32x16 acc[4];
    #pragma unroll
    for (int n = 0; n < 4; ++n)
        #pragma unroll
        for (int i = 0; i < 16; ++i) acc[n][i] = 0.f;

    #pragma unroll
    for (int k0 = 0; k0 < D; k0 += 16) {
        bf16x8 af0 = *(const bf16x8*)(a0 + k0);
        bf16x8 af1, af2;
        if constexpr (NMAT > 1) af1 = *(const bf16x8*)(a1 + k0);
        if constexpr (NMAT > 2) af2 = *(const bf16x8*)(a2 + k0);
        #pragma unroll
        for (int n = 0; n < 4; ++n) {
            const bf16* wrow = W + (size_t)(n * 32 + m) * D + k0 + half * 8;
            {
                bf16x8 bh = *(const bf16x8*)(wrow);
                bf16x8 blo = *(const bf16x8*)(wrow + D * D);
                acc[n] = __builtin_amdgcn_mfma_f32_32x32x16_bf16(af0, bh, acc[n], 0, 0, 0);
                acc[n] = __builtin_amdgcn_mfma_f32_32x32x16_bf16(af0, blo, acc[n], 0, 0, 0);
            }
            if constexpr (NMAT > 1) {
                bf16x8 bh = *(const bf16x8*)(wrow + 2 * D * D);
                bf16x8 blo = *(const bf16x8*)(wrow + 3 * D * D);
                acc[n] = __builtin_amdgcn_mfma_f32_32x32x16_bf16(af1, bh, acc[n], 0, 0, 0);
                acc[n] = __builtin_amdgcn_mfma_f32_32x32x16_bf16(af1, blo, acc[n], 0, 0, 0);
            }
            if constexpr (NMAT > 2) {
                bf16x8 bh = *(const bf16x8*)(wrow + 4 * D * D);
                bf16x8 blo = *(const bf16x8*)(wrow + 5 * D * D);
                acc[n] = __builtin_amdgcn_mfma_f32_32x32x16_bf16(af2, bh, acc[n], 0, 0, 0);
                acc[n] = __builtin_amdgcn_mfma_f32_32x32x16_bf16(af2, blo, acc[n], 0, 0, 0);
            }
        }
    }

    #pragma unroll
    for (int n = 0; n < 4; ++n) {
        int col = n * 32 + m;
        float bv = bias[col];
        #pragma unroll
        for (int r = 0; r < 16; ++r) {
            int row = (r & 3) + 8 * (r >> 2) + 4 * half;
            int grow = row0 + row;
            if (grow < M) out[(size_t)grow * D + col] = (bf16)(acc[n][r] + bv);
        }
    }
}

// ---------------- pooling: sorted batch ids; 128 threads (one per col), 64 rows/block -
__global__ void pool_bf16(const bf16* __restrict__ x, const int* __restrict__ batch,
                          float* __restrict__ pooled, int n, int chunk) {
    int c = threadIdx.x;  // 0..127
    int r0 = blockIdx.x * chunk;
    int r1 = min(r0 + chunk, n);
    if (r0 >= r1) return;
    int cur = batch[r0];
    float acc = 0.f;
    for (int r = r0; r < r1; ++r) {
        int b = batch[r];
        if (b != cur) { atomicAdd(&pooled[cur * D + c], acc); acc = 0.f; cur = b; }
        acc += (float)x[(size_t)r * D + c];
    }
    atomicAdd(&pooled[cur * D + c], acc);
}

// ---------------- head: relu(pooled @ W1^T + b1) @ W2^T + b2 (fp32) ----------------
__global__ void head_kernel(const float* __restrict__ pooled, const float* __restrict__ W1,
                            const float* __restrict__ b1, const float* __restrict__ W2,
                            const float* __restrict__ b2, float* __restrict__ out) {
    __shared__ float p[D];
    __shared__ float h[D];
    int b = blockIdx.x, t = threadIdx.x;  // 128 threads
    p[t] = pooled[b * D + t];
    __syncthreads();
    float s = b1[t];
    const float* w = W1 + (size_t)t * D;
    #pragma unroll 4
    for (int k = 0; k < D; ++k) s += p[k] * w[k];
    h[t] = fmaxf(s, 0.f);
    __syncthreads();
    if (t < OUTD) {
        float s2 = b2[t];
        const float* w2 = W2 + (size_t)t * D;
        #pragma unroll 4
        for (int k = 0; k < D; ++k) s2 += h[k] * w2[k];
        out[b * OUTD + t] = s2;
    }
}

extern "C" void kernel_launch(void* const* d_in, const int* in_sizes, int n_in,
                              void* d_out, int out_size, void* d_ws, size_t ws_size,
                              hipStream_t stream) {
    const int* event_ids   = (const int*)d_in[0];
    const int* trace_ids   = (const int*)d_in[1];
    const int* e2e_src     = (const int*)d_in[2];
    const int* e2e_dst     = (const int*)d_in[3];
    const int* e2t_src     = (const int*)d_in[4];
    const int* e2t_dst     = (const int*)d_in[5];
    const int* t2e_src     = (const int*)d_in[6];
    const int* t2e_dst     = (const int*)d_in[7];
    const int* event_batch = (const int*)d_in[8];
    const int* trace_batch = (const int*)d_in[9];
    const float* emb_event = (const float*)d_in[10];
    const float* emb_trace = (const float*)d_in[11];
    const float* Wl        = (const float*)d_in[12];
    const float* bl        = (const float*)d_in[13];
    const float* Wr        = (const float*)d_in[14];
    const float* W1        = (const float*)d_in[15];
    const float* b1        = (const float*)d_in[16];
    const float* W2        = (const float*)d_in[17];
    const float* b2        = (const float*)d_in[18];

    const int NE = in_sizes[0];
    const int NT = in_sizes[1];
    const int EE = in_sizes[2];
    const int ET = in_sizes[4];
    const int TE = in_sizes[6];

    // ---- workspace carve-up ----
    size_t cur = 0;
    auto alloc = [&](size_t bytes) -> void* {
        cur = (cur + 255) & ~(size_t)255;
        void* p = (char*)d_ws + cur;
        cur += bytes;
        return p;
    };
    bf16* x_event   = (bf16*)alloc((size_t)NE * D * 2);
    bf16* x_trace   = (bf16*)alloc((size_t)NT * D * 2);
    bf16* nx_event  = (bf16*)alloc((size_t)NE * D * 2);
    bf16* nx_trace  = (bf16*)alloc((size_t)NT * D * 2);
    bf16* m_ee      = (bf16*)alloc((size_t)NE * D * 2);
    bf16* m_te      = (bf16*)alloc((size_t)NE * D * 2);
    bf16* m_et      = (bf16*)alloc((size_t)NT * D * 2);
    float* pooled   = (float*)alloc((size_t)NB * D * 4);
    bf16* wbuf      = (bf16*)alloc((size_t)NLAY * 10 * D * D * 2);
    float* bbuf     = (float*)alloc((size_t)NLAY * 2 * D * 4);
    int* deg_ee = (int*)alloc((size_t)NE * 4);
    int* off_ee = (int*)alloc((size_t)(NE + 1) * 4);
    int* cur_ee = (int*)alloc((size_t)NE * 4);
    int* adj_ee = (int*)alloc((size_t)EE * 4);
    int* deg_et = (int*)alloc((size_t)NT * 4);
    int* off_et = (int*)alloc((size_t)(NT + 1) * 4);
    int* cur_et = (int*)alloc((size_t)NT * 4);
    int* adj_et = (int*)alloc((size_t)ET * 4);
    int* deg_te = (int*)alloc((size_t)NE * 4);
    int* off_te = (int*)alloc((size_t)(NE + 1) * 4);
    int* cur_te = (int*)alloc((size_t)NE * 4);
    int* adj_te = (int*)alloc((size_t)TE * 4);
    int* bsum_ee = (int*)alloc(((size_t)(NE + 1023) / 1024 + 1) * 4);
    int* bsum_et = (int*)alloc(((size_t)(NT + 1023) / 1024 + 1) * 4);
    int* bsum_te = (int*)alloc(((size_t)(NE + 1023) / 1024 + 1) * 4);
    (void)ws_size; (void)n_in; (void)out_size;

    const int nbE = (NE + 1023) / 1024;
    const int nbT = (NT + 1023) / 1024;

    // ---- initial embeddings (fp32 -> bf16) ----
    gather_to_bf16<<<(NE * D + 255) / 256, 256, 0, stream>>>(emb_event, event_ids, x_event, NE);
    gather_to_bf16<<<(NT * D + 255) / 256, 256, 0, stream>>>(emb_trace, trace_ids, x_trace, NT);

    // ---- weight prep ----
    prep_weights<<<(NLAY * D * D + 255) / 256, 256, 0, stream>>>(Wl, Wr, bl, wbuf, bbuf);

    // ---- CSR build ----
    hipMemsetAsync(deg_ee, 0, (size_t)NE * 4, stream);
    hipMemsetAsync(deg_et, 0, (size_t)NT * 4, stream);
    hipMemsetAsync(deg_te, 0, (size_t)NE * 4, stream);
    hist_kernel<<<(EE + 255) / 256, 256, 0, stream>>>(e2e_dst, deg_ee, EE);
    hist_kernel<<<(ET + 255) / 256, 256, 0, stream>>>(e2t_dst, deg_et, ET);
    hist_kernel<<<(TE + 255) / 256, 256, 0, stream>>>(t2e_dst, deg_te, TE);
    scan_phase1<<<nbE, 256, 0, stream>>>(deg_ee, off_ee, bsum_ee, NE);
    scan_phase1<<<nbT, 256, 0, stream>>>(deg_et, off_et, bsum_et, NT);
    scan_phase1<<<nbE, 256, 0, stream>>>(deg_te, off_te, bsum_te, NE);
    scan_phase2<<<1, 256, 0, stream>>>(bsum_ee, nbE);
    scan_phase2<<<1, 256, 0, stream>>>(bsum_et, nbT);
    scan_phase2<<<1, 256, 0, stream>>>(bsum_te, nbE);
    scan_phase3<<<(NE + 255) / 256, 256, 0, stream>>>(off_ee, cur_ee, bsum_ee, NE);
    scan_phase3<<<(NT + 255) / 256, 256, 0, stream>>>(off_et, cur_et, bsum_et, NT);
    scan_phase3<<<(NE + 255) / 256, 256, 0, stream>>>(off_te, cur_te, bsum_te, NE);
    fill_adj<<<(EE + 255) / 256, 256, 0, stream>>>(e2e_src, e2e_dst, cur_ee, adj_ee, EE);
    fill_adj<<<(ET + 255) / 256, 256, 0, stream>>>(e2t_src, e2t_dst, cur_et, adj_et, ET);
    fill_adj<<<(TE + 255) / 256, 256, 0, stream>>>(t2e_src, t2e_dst, cur_te, adj_te, TE);

    // ---- layers ----
    for (int l = 0; l < NLAY; ++l) {
        const bf16* wl_ev = wbuf + (size_t)l * 10 * D * D;       // Wl0, Wl2, WrS (hi/lo each)
        const bf16* wl_tr = wl_ev + (size_t)6 * D * D;           // Wl1, Wr1 (hi/lo each)
        const float* be = bbuf + (size_t)l * 2 * D;
        const float* bt = be + D;

        agg_mean_bf16<<<(NE + 3) / 4, 256, 0, stream>>>(x_event, off_ee, adj_ee, m_ee, NE);
        agg_mean_bf16<<<(NE + 3) / 4, 256, 0, stream>>>(x_trace, off_te, adj_te, m_te, NE);
        agg_mean_bf16<<<(NT + 3) / 4, 256, 0, stream>>>(x_event, off_et, adj_et, m_et, NT);

        gemm_fused<3><<<(NE + 127) / 128, 256, 0, stream>>>(m_ee, m_te, x_event, wl_ev, be, nx_event, NE);
        gemm_fused<2><<<(NT + 127) / 128, 256, 0, stream>>>(m_et, x_trace, (const bf16*)nullptr, wl_tr, bt, nx_trace, NT);

        bf16* t;
        t = x_event; x_event = nx_event; nx_event = t;
        t = x_trace; x_trace = nx_trace; nx_trace = t;
    }

    // ---- pooling ----
    hipMemsetAsync(pooled, 0, (size_t)NB * D * 4, stream);
    const int CHUNK = 64;
    pool_bf16<<<(NE + CHUNK - 1) / CHUNK, D, 0, stream>>>(x_event, event_batch, pooled, NE, CHUNK);
    pool_bf16<<<(NT + CHUNK - 1) / CHUNK, D, 0, stream>>>(x_trace, trace_batch, pooled, NT, CHUNK);

    // ---- head ----
    head_kernel<<<NB, D, 0, stream>>>(pooled, W1, b1, W2, b2, (float*)d_out);
}

// Round 3
// 1183.735 us; speedup vs baseline: 2.3153x; 1.2555x over previous
//
#include <hip/hip_runtime.h>
#include <hip/hip_bf16.h>

// HeteroGraphEncoder: 3-layer hetero GraphSAGE + pool + MLP head.
// bf16 activations/weights (hi+lo compensated weights), fp32 accumulation.
// NE=100000, NT=20000, EE=1e6, ET=5e5, TE=5e5, D=128, B=64, OUT=64, L=3.

#define D 128
#define NB 64
#define OUTD 64
#define NLAY 3

typedef __bf16 bf16;
typedef __bf16 bf16x2 __attribute__((ext_vector_type(2)));
typedef __bf16 bf16x8 __attribute__((ext_vector_type(8)));
typedef float  f32x16 __attribute__((ext_vector_type(16)));

#define LOAD16_TO_LDS(gp, lp) \
    __builtin_amdgcn_global_load_lds((const __attribute__((address_space(1))) void*)(gp), \
                                     (__attribute__((address_space(3))) void*)(lp), 16, 0, 0)

// ---------------- initial embedding gather + cvt to bf16 ----------------
__global__ void gather_to_bf16(const float* __restrict__ emb, const int* __restrict__ ids,
                               bf16* __restrict__ x, int n) {
    int idx = blockIdx.x * blockDim.x + threadIdx.x;
    if (idx >= n * D) return;
    int r = idx >> 7;
    int c = idx & (D - 1);
    x[idx] = (bf16)emb[(size_t)ids[r] * D + c];
}

// ---------------- CSR build ----------------
__global__ void hist_kernel(const int* __restrict__ dst, int* __restrict__ deg, int E) {
    int e = blockIdx.x * blockDim.x + threadIdx.x;
    if (e < E) atomicAdd(&deg[dst[e]], 1);
}

__global__ void scan_phase1(const int* __restrict__ deg, int* __restrict__ off,
                            int* __restrict__ bsum, int n) {
    __shared__ int s[256];
    int t = threadIdx.x;
    int base = blockIdx.x * 1024 + t * 4;
    int v[4];
    #pragma unroll
    for (int i = 0; i < 4; ++i) v[i] = (base + i < n) ? deg[base + i] : 0;
    int tot = v[0] + v[1] + v[2] + v[3];
    s[t] = tot;
    __syncthreads();
    for (int st = 1; st < 256; st <<= 1) {
        int x = (t >= st) ? s[t - st] : 0;
        __syncthreads();
        s[t] += x;
        __syncthreads();
    }
    int run = s[t] - tot;
    #pragma unroll
    for (int i = 0; i < 4; ++i) {
        if (base + i < n) off[base + i] = run;
        run += v[i];
    }
    if (t == 255) bsum[blockIdx.x] = s[255];
}

__global__ void scan_phase2(int* __restrict__ bsum, int nb) {  // nb <= 256
    __shared__ int s[256];
    int t = threadIdx.x;
    int v = (t < nb) ? bsum[t] : 0;
    s[t] = v;
    __syncthreads();
    for (int st = 1; st < 256; st <<= 1) {
        int x = (t >= st) ? s[t - st] : 0;
        __syncthreads();
        s[t] += x;
        __syncthreads();
    }
    if (t < nb) bsum[t] = s[t] - v;
    if (t == 0) bsum[nb] = s[255];
}

__global__ void scan_phase3(int* __restrict__ off, int* __restrict__ cur,
                            const int* __restrict__ bsum, int n) {
    int i = blockIdx.x * blockDim.x + threadIdx.x;
    if (i < n) {
        int o = off[i] + bsum[i >> 10];
        off[i] = o;
        cur[i] = o;
    }
    if (i == 0) off[n] = bsum[(n + 1023) >> 10];
}

__global__ void fill_adj(const int* __restrict__ src, const int* __restrict__ dst,
                         int* __restrict__ cur, int* __restrict__ adj, int E) {
    int e = blockIdx.x * blockDim.x + threadIdx.x;
    if (e < E) {
        int p = atomicAdd(&cur[dst[e]], 1);
        adj[p] = src[e];
    }
}

// ---------------- mean aggregation: one wave per dst row; unroll-4 for MLP ----------
__global__ void agg_mean_bf16(const bf16* __restrict__ xsrc, const int* __restrict__ off,
                              const int* __restrict__ adj, bf16* __restrict__ out, int ndst) {
    int wave = (blockIdx.x * blockDim.x + threadIdx.x) >> 6;
    int lane = threadIdx.x & 63;
    if (wave >= ndst) return;
    int s0 = off[wave], s1 = off[wave + 1];
    float ax = 0.f, ay = 0.f;
    int j = s0;
    for (; j + 4 <= s1; j += 4) {
        int i0 = adj[j], i1 = adj[j + 1], i2 = adj[j + 2], i3 = adj[j + 3];
        bf16x2 v0 = ((const bf16x2*)(xsrc + (size_t)i0 * D))[lane];
        bf16x2 v1 = ((const bf16x2*)(xsrc + (size_t)i1 * D))[lane];
        bf16x2 v2 = ((const bf16x2*)(xsrc + (size_t)i2 * D))[lane];
        bf16x2 v3 = ((const bf16x2*)(xsrc + (size_t)i3 * D))[lane];
        ax += (float)v0.x + (float)v1.x + (float)v2.x + (float)v3.x;
        ay += (float)v0.y + (float)v1.y + (float)v2.y + (float)v3.y;
    }
    for (; j < s1; ++j) {
        int s = adj[j];
        bf16x2 v = ((const bf16x2*)(xsrc + (size_t)s * D))[lane];
        ax += (float)v.x;
        ay += (float)v.y;
    }
    float inv = 1.0f / fmaxf((float)(s1 - s0), 1.0f);
    bf16x2 o;
    o.x = (bf16)(ax * inv);
    o.y = (bf16)(ay * inv);
    ((bf16x2*)(out + (size_t)wave * D))[lane] = o;
}

// ---------------- weight prep: split into bf16 hi/lo, fold Wr0+Wr2, biases ----------
// per-layer layout: slot 0/1: Wl0 hi/lo  2/3: Wl2 hi/lo  4/5: WrS hi/lo
//                   slot 6/7: Wl1 hi/lo  8/9: Wr1 hi/lo
__global__ void prep_weights(const float* __restrict__ Wl, const float* __restrict__ Wr,
                             const float* __restrict__ bl, bf16* __restrict__ wbuf,
                             float* __restrict__ bbuf) {
    int idx = blockIdx.x * blockDim.x + threadIdx.x;
    if (idx >= NLAY * D * D) return;
    int l = idx / (D * D), o = idx - l * D * D;
    bf16* base = wbuf + (size_t)l * 10 * D * D;
    float w;
    bf16 h;
    w = Wl[(size_t)(l * 3 + 0) * D * D + o]; h = (bf16)w;
    base[0 * D * D + o] = h; base[1 * D * D + o] = (bf16)(w - (float)h);
    w = Wl[(size_t)(l * 3 + 2) * D * D + o]; h = (bf16)w;
    base[2 * D * D + o] = h; base[3 * D * D + o] = (bf16)(w - (float)h);
    w = Wr[(size_t)(l * 3 + 0) * D * D + o] + Wr[(size_t)(l * 3 + 2) * D * D + o]; h = (bf16)w;
    base[4 * D * D + o] = h; base[5 * D * D + o] = (bf16)(w - (float)h);
    w = Wl[(size_t)(l * 3 + 1) * D * D + o]; h = (bf16)w;
    base[6 * D * D + o] = h; base[7 * D * D + o] = (bf16)(w - (float)h);
    w = Wr[(size_t)(l * 3 + 1) * D * D + o]; h = (bf16)w;
    base[8 * D * D + o] = h; base[9 * D * D + o] = (bf16)(w - (float)h);
    if (o < D) {
        bbuf[l * 2 * D + o]     = bl[(size_t)(l * 3 + 0) * D + o] + bl[(size_t)(l * 3 + 2) * D + o];
        bbuf[l * 2 * D + D + o] = bl[(size_t)(l * 3 + 1) * D + o];
    }
}

// ---------------- fused MFMA GEMM: out = bias + sum_s A_s @ W_s^T ----------------
// 256 threads = 4 waves; block tile 128 rows x 128 cols; K=128 in 8 steps of 16.
// A matrices staged sequentially through one 32 KB LDS buffer via global_load_lds
// (width 16, coalesced). XOR chunk-swizzle on the GATHER side (dest is wave-uniform
// base + lane*16, cannot scatter): LDS slot (row, u) holds global chunk (row, u^(row&15)).
// ds_read_b128 of a fragment then spreads over 8 bank-quads (b128 floor), not 32-way.
// mfma_f32_32x32x16_bf16 C/D: col=lane&31, row=(reg&3)+8*(reg>>2)+4*(lane>>5).
template<int NMAT>
__global__ __launch_bounds__(256) void gemm_fused(const bf16* __restrict__ A0,
                                                  const bf16* __restrict__ A1,
                                                  const bf16* __restrict__ A2,
                                                  const bf16* __restrict__ W,
                                                  const float* __restrict__ bias,
                                                  bf16* __restrict__ out, int M) {
    __shared__ bf16 As[128 * 128];   // 32 KB
    int tid = threadIdx.x;
    int wave = tid >> 6, lane = tid & 63;
    int row0 = blockIdx.x * 128;
    int m = lane & 31, half = lane >> 5;

    f32x16 acc[4];
    #pragma unroll
    for (int n = 0; n < 4; ++n)
        #pragma unroll
        for (int i = 0; i < 16; ++i) acc[n][i] = 0.f;

    const bf16* Aptr[3] = {A0, A1, A2};
    #pragma unroll
    for (int s = 0; s < NMAT; ++s) {
        const bf16* Amat = Aptr[s];
        // ---- stage 128x128 bf16 tile: 8 passes x (4 waves x 1 KB) ----
        #pragma unroll
        for (int p = 0; p < 8; ++p) {
            int si = p * 256 + tid;            // LDS 16B-slot index
            int r = si >> 4, u = si & 15;
            int gr = row0 + r; if (gr >= M) gr = M - 1;
            int gc = (u ^ (r & 15)) * 8;       // swizzled source chunk (elements)
            const bf16* gp = Amat + (size_t)gr * D + gc;
            bf16* lp = As + (size_t)(p * 4 + wave) * 512;   // wave-uniform base (1 KB/wave)
            LOAD16_TO_LDS(gp, lp);
        }
        __syncthreads();   // drains vmcnt incl. global_load_lds

        int r = wave * 32 + m;
        const bf16* Wmat = W + (size_t)(2 * s) * D * D;
        #pragma unroll
        for (int k0 = 0; k0 < D; k0 += 16) {
            int c = (k0 >> 3) + half;                           // logical chunk 0..15
            bf16x8 af = *(const bf16x8*)(As + ((size_t)r * 16 + (c ^ (r & 15))) * 8);
            #pragma unroll
            for (int n = 0; n < 4; ++n) {
                const bf16* wrow = Wmat + (size_t)(n * 32 + m) * D + k0 + half * 8;
                bf16x8 bh  = *(const bf16x8*)(wrow);
                bf16x8 blo = *(const bf16x8*)(wrow + D * D);
                acc[n] = __builtin_amdgcn_mfma_f32_32x32x16_bf16(af, bh, acc[n], 0, 0, 0);
                acc[n] = __builtin_amdgcn_mfma_f32_32x32x16_bf16(af, blo, acc[n], 0, 0, 0);
            }
        }
        if (s + 1 < NMAT) __syncthreads();   // protect LDS before restage
    }

    #pragma unroll
    for (int n = 0; n < 4; ++n) {
        int col = n * 32 + m;
        float bv = bias[col];
        #pragma unroll
        for (int r = 0; r < 16; ++r) {
            int row = (r & 3) + 8 * (r >> 2) + 4 * half;
            int grow = row0 + wave * 32 + row;
            if (grow < M) out[(size_t)grow * D + col] = (bf16)(acc[n][r] + bv);
        }
    }
}

// ---------------- pooling: sorted batch ids; 128 threads (one per col) ----------------
__global__ void pool_bf16(const bf16* __restrict__ x, const int* __restrict__ batch,
                          float* __restrict__ pooled, int n, int chunk) {
    int c = threadIdx.x;  // 0..127
    int r0 = blockIdx.x * chunk;
    int r1 = min(r0 + chunk, n);
    if (r0 >= r1) return;
    int cur = batch[r0];
    float acc = 0.f;
    for (int r = r0; r < r1; ++r) {
        int b = batch[r];
        if (b != cur) { atomicAdd(&pooled[cur * D + c], acc); acc = 0.f; cur = b; }
        acc += (float)x[(size_t)r * D + c];
    }
    atomicAdd(&pooled[cur * D + c], acc);
}

// ---------------- head: relu(pooled @ W1^T + b1) @ W2^T + b2 (fp32) ----------------
__global__ void head_kernel(const float* __restrict__ pooled, const float* __restrict__ W1,
                            const float* __restrict__ b1, const float* __restrict__ W2,
                            const float* __restrict__ b2, float* __restrict__ out) {
    __shared__ float p[D];
    __shared__ float h[D];
    int b = blockIdx.x, t = threadIdx.x;  // 128 threads
    p[t] = pooled[b * D + t];
    __syncthreads();
    float s = b1[t];
    const float* w = W1 + (size_t)t * D;
    #pragma unroll 4
    for (int k = 0; k < D; ++k) s += p[k] * w[k];
    h[t] = fmaxf(s, 0.f);
    __syncthreads();
    if (t < OUTD) {
        float s2 = b2[t];
        const float* w2 = W2 + (size_t)t * D;
        #pragma unroll 4
        for (int k = 0; k < D; ++k) s2 += h[k] * w2[k];
        out[b * OUTD + t] = s2;
    }
}

extern "C" void kernel_launch(void* const* d_in, const int* in_sizes, int n_in,
                              void* d_out, int out_size, void* d_ws, size_t ws_size,
                              hipStream_t stream) {
    const int* event_ids   = (const int*)d_in[0];
    const int* trace_ids   = (const int*)d_in[1];
    const int* e2e_src     = (const int*)d_in[2];
    const int* e2e_dst     = (const int*)d_in[3];
    const int* e2t_src     = (const int*)d_in[4];
    const int* e2t_dst     = (const int*)d_in[5];
    const int* t2e_src     = (const int*)d_in[6];
    const int* t2e_dst     = (const int*)d_in[7];
    const int* event_batch = (const int*)d_in[8];
    const int* trace_batch = (const int*)d_in[9];
    const float* emb_event = (const float*)d_in[10];
    const float* emb_trace = (const float*)d_in[11];
    const float* Wl        = (const float*)d_in[12];
    const float* bl        = (const float*)d_in[13];
    const float* Wr        = (const float*)d_in[14];
    const float* W1        = (const float*)d_in[15];
    const float* b1        = (const float*)d_in[16];
    const float* W2        = (const float*)d_in[17];
    const float* b2        = (const float*)d_in[18];

    const int NE = in_sizes[0];
    const int NT = in_sizes[1];
    const int EE = in_sizes[2];
    const int ET = in_sizes[4];
    const int TE = in_sizes[6];

    // ---- workspace carve-up ----
    size_t cur = 0;
    auto alloc = [&](size_t bytes) -> void* {
        cur = (cur + 255) & ~(size_t)255;
        void* p = (char*)d_ws + cur;
        cur += bytes;
        return p;
    };
    bf16* x_event   = (bf16*)alloc((size_t)NE * D * 2);
    bf16* x_trace   = (bf16*)alloc((size_t)NT * D * 2);
    bf16* nx_event  = (bf16*)alloc((size_t)NE * D * 2);
    bf16* nx_trace  = (bf16*)alloc((size_t)NT * D * 2);
    bf16* m_ee      = (bf16*)alloc((size_t)NE * D * 2);
    bf16* m_te      = (bf16*)alloc((size_t)NE * D * 2);
    bf16* m_et      = (bf16*)alloc((size_t)NT * D * 2);
    float* pooled   = (float*)alloc((size_t)NB * D * 4);
    bf16* wbuf      = (bf16*)alloc((size_t)NLAY * 10 * D * D * 2);
    float* bbuf     = (float*)alloc((size_t)NLAY * 2 * D * 4);
    int* deg_ee = (int*)alloc((size_t)NE * 4);
    int* off_ee = (int*)alloc((size_t)(NE + 1) * 4);
    int* cur_ee = (int*)alloc((size_t)NE * 4);
    int* adj_ee = (int*)alloc((size_t)EE * 4);
    int* deg_et = (int*)alloc((size_t)NT * 4);
    int* off_et = (int*)alloc((size_t)(NT + 1) * 4);
    int* cur_et = (int*)alloc((size_t)NT * 4);
    int* adj_et = (int*)alloc((size_t)ET * 4);
    int* deg_te = (int*)alloc((size_t)NE * 4);
    int* off_te = (int*)alloc((size_t)(NE + 1) * 4);
    int* cur_te = (int*)alloc((size_t)NE * 4);
    int* adj_te = (int*)alloc((size_t)TE * 4);
    int* bsum_ee = (int*)alloc(((size_t)(NE + 1023) / 1024 + 1) * 4);
    int* bsum_et = (int*)alloc(((size_t)(NT + 1023) / 1024 + 1) * 4);
    int* bsum_te = (int*)alloc(((size_t)(NE + 1023) / 1024 + 1) * 4);
    (void)ws_size; (void)n_in; (void)out_size;

    const int nbE = (NE + 1023) / 1024;
    const int nbT = (NT + 1023) / 1024;

    // ---- initial embeddings (fp32 -> bf16) ----
    gather_to_bf16<<<(NE * D + 255) / 256, 256, 0, stream>>>(emb_event, event_ids, x_event, NE);
    gather_to_bf16<<<(NT * D + 255) / 256, 256, 0, stream>>>(emb_trace, trace_ids, x_trace, NT);

    // ---- weight prep ----
    prep_weights<<<(NLAY * D * D + 255) / 256, 256, 0, stream>>>(Wl, Wr, bl, wbuf, bbuf);

    // ---- CSR build ----
    hipMemsetAsync(deg_ee, 0, (size_t)NE * 4, stream);
    hipMemsetAsync(deg_et, 0, (size_t)NT * 4, stream);
    hipMemsetAsync(deg_te, 0, (size_t)NE * 4, stream);
    hist_kernel<<<(EE + 255) / 256, 256, 0, stream>>>(e2e_dst, deg_ee, EE);
    hist_kernel<<<(ET + 255) / 256, 256, 0, stream>>>(e2t_dst, deg_et, ET);
    hist_kernel<<<(TE + 255) / 256, 256, 0, stream>>>(t2e_dst, deg_te, TE);
    scan_phase1<<<nbE, 256, 0, stream>>>(deg_ee, off_ee, bsum_ee, NE);
    scan_phase1<<<nbT, 256, 0, stream>>>(deg_et, off_et, bsum_et, NT);
    scan_phase1<<<nbE, 256, 0, stream>>>(deg_te, off_te, bsum_te, NE);
    scan_phase2<<<1, 256, 0, stream>>>(bsum_ee, nbE);
    scan_phase2<<<1, 256, 0, stream>>>(bsum_et, nbT);
    scan_phase2<<<1, 256, 0, stream>>>(bsum_te, nbE);
    scan_phase3<<<(NE + 255) / 256, 256, 0, stream>>>(off_ee, cur_ee, bsum_ee, NE);
    scan_phase3<<<(NT + 255) / 256, 256, 0, stream>>>(off_et, cur_et, bsum_et, NT);
    scan_phase3<<<(NE + 255) / 256, 256, 0, stream>>>(off_te, cur_te, bsum_te, NE);
    fill_adj<<<(EE + 255) / 256, 256, 0, stream>>>(e2e_src, e2e_dst, cur_ee, adj_ee, EE);
    fill_adj<<<(ET + 255) / 256, 256, 0, stream>>>(e2t_src, e2t_dst, cur_et, adj_et, ET);
    fill_adj<<<(TE + 255) / 256, 256, 0, stream>>>(t2e_src, t2e_dst, cur_te, adj_te, TE);

    // ---- layers ----
    for (int l = 0; l < NLAY; ++l) {
        const bf16* wl_ev = wbuf + (size_t)l * 10 * D * D;   // Wl0, Wl2, WrS (hi/lo each)
        const bf16* wl_tr = wl_ev + (size_t)6 * D * D;       // Wl1, Wr1 (hi/lo each)
        const float* be = bbuf + (size_t)l * 2 * D;
        const float* bt = be + D;

        agg_mean_bf16<<<(NE + 3) / 4, 256, 0, stream>>>(x_event, off_ee, adj_ee, m_ee, NE);
        agg_mean_bf16<<<(NE + 3) / 4, 256, 0, stream>>>(x_trace, off_te, adj_te, m_te, NE);
        agg_mean_bf16<<<(NT + 3) / 4, 256, 0, stream>>>(x_event, off_et, adj_et, m_et, NT);

        gemm_fused<3><<<(NE + 127) / 128, 256, 0, stream>>>(m_ee, m_te, x_event, wl_ev, be, nx_event, NE);
        gemm_fused<2><<<(NT + 127) / 128, 256, 0, stream>>>(m_et, x_trace, (const bf16*)nullptr, wl_tr, bt, nx_trace, NT);

        bf16* t;
        t = x_event; x_event = nx_event; nx_event = t;
        t = x_trace; x_trace = nx_trace; nx_trace = t;
    }

    // ---- pooling ----
    hipMemsetAsync(pooled, 0, (size_t)NB * D * 4, stream);
    const int CHUNK = 64;
    pool_bf16<<<(NE + CHUNK - 1) / CHUNK, D, 0, stream>>>(x_event, event_batch, pooled, NE, CHUNK);
    pool_bf16<<<(NT + CHUNK - 1) / CHUNK, D, 0, stream>>>(x_trace, trace_batch, pooled, NT, CHUNK);

    // ---- head ----
    head_kernel<<<NB, D, 0, stream>>>(pooled, W1, b1, W2, b2, (float*)d_out);
}

// Round 4
// 854.805 us; speedup vs baseline: 3.2063x; 1.3848x over previous
//
#include <hip/hip_runtime.h>
#include <hip/hip_bf16.h>

// HeteroGraphEncoder: 3-layer hetero GraphSAGE + pool + MLP head.
// bf16 activations/weights (hi+lo compensated weights), fp32 accumulation.
// NE=100000, NT=20000, EE=1e6, ET=5e5, TE=5e5, D=128, B=64, OUT=64, L=3.

#define D 128
#define NB 64
#define OUTD 64
#define NLAY 3

typedef __bf16 bf16;
typedef __bf16 bf16x8 __attribute__((ext_vector_type(8)));
typedef float  f32x16 __attribute__((ext_vector_type(16)));

#define LOAD16_TO_LDS(gp, lp) \
    __builtin_amdgcn_global_load_lds((const __attribute__((address_space(1))) void*)(gp), \
                                     (__attribute__((address_space(3))) void*)(lp), 16, 0, 0)

// ---------------- initial embedding gather + cvt to bf16 ----------------
__global__ void gather_to_bf16(const float* __restrict__ emb, const int* __restrict__ ids,
                               bf16* __restrict__ x, int n) {
    int idx = blockIdx.x * blockDim.x + threadIdx.x;
    if (idx >= n * D) return;
    int r = idx >> 7;
    int c = idx & (D - 1);
    x[idx] = (bf16)emb[(size_t)ids[r] * D + c];
}

// ---------------- CSR build ----------------
__global__ void hist_kernel(const int* __restrict__ dst, int* __restrict__ deg, int E) {
    int e = blockIdx.x * blockDim.x + threadIdx.x;
    if (e < E) atomicAdd(&deg[dst[e]], 1);
}

__global__ void scan_phase1(const int* __restrict__ deg, int* __restrict__ off,
                            int* __restrict__ bsum, int n) {
    __shared__ int s[256];
    int t = threadIdx.x;
    int base = blockIdx.x * 1024 + t * 4;
    int v[4];
    #pragma unroll
    for (int i = 0; i < 4; ++i) v[i] = (base + i < n) ? deg[base + i] : 0;
    int tot = v[0] + v[1] + v[2] + v[3];
    s[t] = tot;
    __syncthreads();
    for (int st = 1; st < 256; st <<= 1) {
        int x = (t >= st) ? s[t - st] : 0;
        __syncthreads();
        s[t] += x;
        __syncthreads();
    }
    int run = s[t] - tot;
    #pragma unroll
    for (int i = 0; i < 4; ++i) {
        if (base + i < n) off[base + i] = run;
        run += v[i];
    }
    if (t == 255) bsum[blockIdx.x] = s[255];
}

__global__ void scan_phase2(int* __restrict__ bsum, int nb) {  // nb <= 256
    __shared__ int s[256];
    int t = threadIdx.x;
    int v = (t < nb) ? bsum[t] : 0;
    s[t] = v;
    __syncthreads();
    for (int st = 1; st < 256; st <<= 1) {
        int x = (t >= st) ? s[t - st] : 0;
        __syncthreads();
        s[t] += x;
        __syncthreads();
    }
    if (t < nb) bsum[t] = s[t] - v;
    if (t == 0) bsum[nb] = s[255];
}

__global__ void scan_phase3(int* __restrict__ off, int* __restrict__ cur,
                            const int* __restrict__ bsum, int n) {
    int i = blockIdx.x * blockDim.x + threadIdx.x;
    if (i < n) {
        int o = off[i] + bsum[i >> 10];
        off[i] = o;
        cur[i] = o;
    }
    if (i == 0) off[n] = bsum[(n + 1023) >> 10];
}

__global__ void fill_adj(const int* __restrict__ src, const int* __restrict__ dst,
                         int* __restrict__ cur, int* __restrict__ adj, int E) {
    int e = blockIdx.x * blockDim.x + threadIdx.x;
    if (e < E) {
        int p = atomicAdd(&cur[dst[e]], 1);
        adj[p] = src[e];
    }
}

// ---------------- mean aggregation: 4 dst rows per wave, 16 lanes (bf16x8) per row ----
// 16 independent 256B row-streams in flight per wave (4 rows x unroll-4).
__global__ void agg_mean_bf16(const bf16* __restrict__ xsrc, const int* __restrict__ off,
                              const int* __restrict__ adj, bf16* __restrict__ out, int ndst) {
    int gw = (blockIdx.x * blockDim.x + threadIdx.x) >> 6;
    int lane = threadIdx.x & 63;
    int sub = lane >> 4;       // 0..3: which dst row
    int sl  = lane & 15;       // 16B chunk within row
    int row = gw * 4 + sub;
    if (row >= ndst) row = ndst - 1;   // duplicate work, identical writes: benign
    int s0 = off[row], s1 = off[row + 1];
    float a[8] = {};
    int j = s0;
    for (; j + 4 <= s1; j += 4) {
        int i0 = adj[j], i1 = adj[j + 1], i2 = adj[j + 2], i3 = adj[j + 3];
        bf16x8 v0 = ((const bf16x8*)(xsrc + (size_t)i0 * D))[sl];
        bf16x8 v1 = ((const bf16x8*)(xsrc + (size_t)i1 * D))[sl];
        bf16x8 v2 = ((const bf16x8*)(xsrc + (size_t)i2 * D))[sl];
        bf16x8 v3 = ((const bf16x8*)(xsrc + (size_t)i3 * D))[sl];
        #pragma unroll
        for (int e = 0; e < 8; ++e)
            a[e] += (float)v0[e] + (float)v1[e] + (float)v2[e] + (float)v3[e];
    }
    for (; j < s1; ++j) {
        int i0 = adj[j];
        bf16x8 v0 = ((const bf16x8*)(xsrc + (size_t)i0 * D))[sl];
        #pragma unroll
        for (int e = 0; e < 8; ++e) a[e] += (float)v0[e];
    }
    float inv = 1.0f / fmaxf((float)(s1 - s0), 1.0f);
    bf16x8 o;
    #pragma unroll
    for (int e = 0; e < 8; ++e) o[e] = (bf16)(a[e] * inv);
    ((bf16x8*)(out + (size_t)row * D))[sl] = o;
}

// ---------------- weight prep: hi/lo split, packed in MFMA fragment order ----------
// Per layer, 5 logical matrices -> 10 slots (hi/lo interleaved by slot pairs):
//   mat 0: Wl0  mat 1: Wl2  mat 2: Wr0+Wr2  mat 3: Wl1  mat 4: Wr1
//   slot 2*mat = hi, slot 2*mat+1 = lo; each slot 16384 bf16.
// Fragment order: chunk q = (w*8 + t)*64 + lane holds W[w*32+(lane&31)][t*16+(lane>>5)*8 .. +8]
// so a wave's B-fragment load for (w,t) is one fully-coalesced 1KB instruction.
__global__ void prep_weights_packed(const float* __restrict__ Wl, const float* __restrict__ Wr,
                                    bf16* __restrict__ wbuf) {
    int idx = blockIdx.x * blockDim.x + threadIdx.x;  // NLAY*5*2048
    if (idx >= NLAY * 5 * 2048) return;
    int l = idx / (5 * 2048);
    int rem = idx - l * 5 * 2048;
    int mat = rem >> 11;     // 0..4
    int q = rem & 2047;
    int lane = q & 63, t = (q >> 6) & 7, w = q >> 9;
    int r = w * 32 + (lane & 31);
    int c = t * 16 + (lane >> 5) * 8;
    size_t l3 = (size_t)l * 3;
    const float* s0;
    const float* s1 = nullptr;
    switch (mat) {
        case 0: s0 = Wl + (l3 + 0) * D * D; break;
        case 1: s0 = Wl + (l3 + 2) * D * D; break;
        case 2: s0 = Wr + (l3 + 0) * D * D; s1 = Wr + (l3 + 2) * D * D; break;
        case 3: s0 = Wl + (l3 + 1) * D * D; break;
        default: s0 = Wr + (l3 + 1) * D * D; break;
    }
    bf16x8 hi, lo;
    #pragma unroll
    for (int e = 0; e < 8; ++e) {
        float v = s0[r * D + c + e];
        if (s1) v += s1[r * D + c + e];
        bf16 h = (bf16)v;
        hi[e] = h;
        lo[e] = (bf16)(v - (float)h);
    }
    bf16* base = wbuf + (size_t)l * 10 * D * D;
    ((bf16x8*)(base + (size_t)(2 * mat) * D * D))[q] = hi;
    ((bf16x8*)(base + (size_t)(2 * mat + 1) * D * D))[q] = lo;
}

__global__ void prep_bias(const float* __restrict__ bl, float* __restrict__ bbuf) {
    int idx = blockIdx.x * blockDim.x + threadIdx.x;  // NLAY*D
    if (idx >= NLAY * D) return;
    int l = idx >> 7, o = idx & (D - 1);
    bbuf[l * 2 * D + o]     = bl[(size_t)(l * 3 + 0) * D + o] + bl[(size_t)(l * 3 + 2) * D + o];
    bbuf[l * 2 * D + D + o] = bl[(size_t)(l * 3 + 1) * D + o];
}

// ---------------- fused MFMA GEMM: out = bias + sum_s A_s @ W_s^T ----------------
// 256 threads = 4 waves; block tile 128 rows x 128 cols.
// N-split across waves: wave w owns cols w*32..w*32+31 and loops 4 row-tiles.
// Per s: B fragments for the wave's slice (16 coalesced 1KB loads from packed wbuf)
// preloaded into registers; A tile staged to LDS via global_load_lds w16 with XOR
// chunk swizzle; inner loop is pure ds_read_b128 + MFMA (VMEM-free).
// mfma_f32_32x32x16_bf16 C/D: col=lane&31, row=(reg&3)+8*(reg>>2)+4*(lane>>5).
template<int NMAT>
__global__ __launch_bounds__(256) void gemm_fused(const bf16* __restrict__ A0,
                                                  const bf16* __restrict__ A1,
                                                  const bf16* __restrict__ A2,
                                                  const bf16* __restrict__ Wp,
                                                  const float* __restrict__ bias,
                                                  bf16* __restrict__ out, int M) {
    __shared__ bf16 As[128 * 128];   // 32 KB
    int tid = threadIdx.x;
    int wave = tid >> 6, lane = tid & 63;
    int row0 = blockIdx.x * 128;
    int m = lane & 31, half = lane >> 5;

    f32x16 acc[4];
    #pragma unroll
    for (int rt = 0; rt < 4; ++rt)
        #pragma unroll
        for (int i = 0; i < 16; ++i) acc[rt][i] = 0.f;

    const bf16* Aptr[3] = {A0, A1, A2};
    #pragma unroll
    for (int s = 0; s < NMAT; ++s) {
        if (s) __syncthreads();   // all waves done reading As before restage
        // ---- B-fragment preload (registers), fully coalesced from packed layout ----
        const bf16* wph = Wp + (size_t)(2 * s) * D * D + ((size_t)wave * 512 + lane) * 8;
        const bf16* wpl = wph + D * D;
        bf16x8 bh[8], blo[8];
        #pragma unroll
        for (int t = 0; t < 8; ++t) {
            bh[t]  = *(const bf16x8*)(wph + t * 512);
            blo[t] = *(const bf16x8*)(wpl + t * 512);
        }
        // ---- stage A tile 128x128: 8 passes x (4 waves x 1 KB) ----
        const bf16* Amat = Aptr[s];
        #pragma unroll
        for (int p = 0; p < 8; ++p) {
            int si = p * 256 + tid;            // LDS 16B-slot index
            int r = si >> 4, u = si & 15;
            int gr = row0 + r; if (gr >= M) gr = M - 1;
            int gc = (u ^ (r & 15)) * 8;       // swizzled source chunk
            LOAD16_TO_LDS(Amat + (size_t)gr * D + gc, As + (size_t)(p * 4 + wave) * 512);
        }
        __syncthreads();   // drains vmcnt (B regs + LDS staging)

        #pragma unroll
        for (int t = 0; t < 8; ++t) {
            bf16x8 af[4];
            #pragma unroll
            for (int rt = 0; rt < 4; ++rt) {
                int r = rt * 32 + m;
                int c = t * 2 + half;
                af[rt] = *(const bf16x8*)(As + ((size_t)r * 16 + (c ^ (r & 15))) * 8);
            }
            #pragma unroll
            for (int rt = 0; rt < 4; ++rt)
                acc[rt] = __builtin_amdgcn_mfma_f32_32x32x16_bf16(af[rt], bh[t], acc[rt], 0, 0, 0);
            #pragma unroll
            for (int rt = 0; rt < 4; ++rt)
                acc[rt] = __builtin_amdgcn_mfma_f32_32x32x16_bf16(af[rt], blo[t], acc[rt], 0, 0, 0);
        }
    }

    int col = wave * 32 + m;
    float bv = bias[col];
    #pragma unroll
    for (int rt = 0; rt < 4; ++rt) {
        #pragma unroll
        for (int r = 0; r < 16; ++r) {
            int row = row0 + rt * 32 + (r & 3) + 8 * (r >> 2) + 4 * half;
            if (row < M) out[(size_t)row * D + col] = (bf16)(acc[rt][r] + bv);
        }
    }
}

// ---------------- pooling: sorted batch ids; 128 threads (one per col) ----------------
__global__ void pool_bf16(const bf16* __restrict__ x, const int* __restrict__ batch,
                          float* __restrict__ pooled, int n, int chunk) {
    int c = threadIdx.x;  // 0..127
    int r0 = blockIdx.x * chunk;
    int r1 = min(r0 + chunk, n);
    if (r0 >= r1) return;
    int cur = batch[r0];
    float acc = 0.f;
    for (int r = r0; r < r1; ++r) {
        int b = batch[r];
        if (b != cur) { atomicAdd(&pooled[cur * D + c], acc); acc = 0.f; cur = b; }
        acc += (float)x[(size_t)r * D + c];
    }
    atomicAdd(&pooled[cur * D + c], acc);
}

// ---------------- head: relu(pooled @ W1^T + b1) @ W2^T + b2 (fp32) ----------------
__global__ void head_kernel(const float* __restrict__ pooled, const float* __restrict__ W1,
                            const float* __restrict__ b1, const float* __restrict__ W2,
                            const float* __restrict__ b2, float* __restrict__ out) {
    __shared__ float p[D];
    __shared__ float h[D];
    int b = blockIdx.x, t = threadIdx.x;  // 128 threads
    p[t] = pooled[b * D + t];
    __syncthreads();
    float s = b1[t];
    const float* w = W1 + (size_t)t * D;
    #pragma unroll 4
    for (int k = 0; k < D; ++k) s += p[k] * w[k];
    h[t] = fmaxf(s, 0.f);
    __syncthreads();
    if (t < OUTD) {
        float s2 = b2[t];
        const float* w2 = W2 + (size_t)t * D;
        #pragma unroll 4
        for (int k = 0; k < D; ++k) s2 += h[k] * w2[k];
        out[b * OUTD + t] = s2;
    }
}

extern "C" void kernel_launch(void* const* d_in, const int* in_sizes, int n_in,
                              void* d_out, int out_size, void* d_ws, size_t ws_size,
                              hipStream_t stream) {
    const int* event_ids   = (const int*)d_in[0];
    const int* trace_ids   = (const int*)d_in[1];
    const int* e2e_src     = (const int*)d_in[2];
    const int* e2e_dst     = (const int*)d_in[3];
    const int* e2t_src     = (const int*)d_in[4];
    const int* e2t_dst     = (const int*)d_in[5];
    const int* t2e_src     = (const int*)d_in[6];
    const int* t2e_dst     = (const int*)d_in[7];
    const int* event_batch = (const int*)d_in[8];
    const int* trace_batch = (const int*)d_in[9];
    const float* emb_event = (const float*)d_in[10];
    const float* emb_trace = (const float*)d_in[11];
    const float* Wl        = (const float*)d_in[12];
    const float* bl        = (const float*)d_in[13];
    const float* Wr        = (const float*)d_in[14];
    const float* W1        = (const float*)d_in[15];
    const float* b1        = (const float*)d_in[16];
    const float* W2        = (const float*)d_in[17];
    const float* b2        = (const float*)d_in[18];

    const int NE = in_sizes[0];
    const int NT = in_sizes[1];
    const int EE = in_sizes[2];
    const int ET = in_sizes[4];
    const int TE = in_sizes[6];

    // ---- workspace carve-up ----
    size_t cur = 0;
    auto alloc = [&](size_t bytes) -> void* {
        cur = (cur + 255) & ~(size_t)255;
        void* p = (char*)d_ws + cur;
        cur += bytes;
        return p;
    };
    bf16* x_event   = (bf16*)alloc((size_t)NE * D * 2);
    bf16* x_trace   = (bf16*)alloc((size_t)NT * D * 2);
    bf16* nx_event  = (bf16*)alloc((size_t)NE * D * 2);
    bf16* nx_trace  = (bf16*)alloc((size_t)NT * D * 2);
    bf16* m_ee      = (bf16*)alloc((size_t)NE * D * 2);
    bf16* m_te      = (bf16*)alloc((size_t)NE * D * 2);
    bf16* m_et      = (bf16*)alloc((size_t)NT * D * 2);
    float* pooled   = (float*)alloc((size_t)NB * D * 4);
    bf16* wbuf      = (bf16*)alloc((size_t)NLAY * 10 * D * D * 2);
    float* bbuf     = (float*)alloc((size_t)NLAY * 2 * D * 4);
    int* deg_ee = (int*)alloc((size_t)NE * 4);
    int* off_ee = (int*)alloc((size_t)(NE + 1) * 4);
    int* cur_ee = (int*)alloc((size_t)NE * 4);
    int* adj_ee = (int*)alloc((size_t)EE * 4);
    int* deg_et = (int*)alloc((size_t)NT * 4);
    int* off_et = (int*)alloc((size_t)(NT + 1) * 4);
    int* cur_et = (int*)alloc((size_t)NT * 4);
    int* adj_et = (int*)alloc((size_t)ET * 4);
    int* deg_te = (int*)alloc((size_t)NE * 4);
    int* off_te = (int*)alloc((size_t)(NE + 1) * 4);
    int* cur_te = (int*)alloc((size_t)NE * 4);
    int* adj_te = (int*)alloc((size_t)TE * 4);
    int* bsum_ee = (int*)alloc(((size_t)(NE + 1023) / 1024 + 1) * 4);
    int* bsum_et = (int*)alloc(((size_t)(NT + 1023) / 1024 + 1) * 4);
    int* bsum_te = (int*)alloc(((size_t)(NE + 1023) / 1024 + 1) * 4);
    (void)ws_size; (void)n_in; (void)out_size;

    const int nbE = (NE + 1023) / 1024;
    const int nbT = (NT + 1023) / 1024;

    // ---- initial embeddings (fp32 -> bf16) ----
    gather_to_bf16<<<(NE * D + 255) / 256, 256, 0, stream>>>(emb_event, event_ids, x_event, NE);
    gather_to_bf16<<<(NT * D + 255) / 256, 256, 0, stream>>>(emb_trace, trace_ids, x_trace, NT);

    // ---- weight prep (packed fragment order) ----
    prep_weights_packed<<<(NLAY * 5 * 2048 + 255) / 256, 256, 0, stream>>>(Wl, Wr, wbuf);
    prep_bias<<<(NLAY * D + 255) / 256, 256, 0, stream>>>(bl, bbuf);

    // ---- CSR build ----
    hipMemsetAsync(deg_ee, 0, (size_t)NE * 4, stream);
    hipMemsetAsync(deg_et, 0, (size_t)NT * 4, stream);
    hipMemsetAsync(deg_te, 0, (size_t)NE * 4, stream);
    hist_kernel<<<(EE + 255) / 256, 256, 0, stream>>>(e2e_dst, deg_ee, EE);
    hist_kernel<<<(ET + 255) / 256, 256, 0, stream>>>(e2t_dst, deg_et, ET);
    hist_kernel<<<(TE + 255) / 256, 256, 0, stream>>>(t2e_dst, deg_te, TE);
    scan_phase1<<<nbE, 256, 0, stream>>>(deg_ee, off_ee, bsum_ee, NE);
    scan_phase1<<<nbT, 256, 0, stream>>>(deg_et, off_et, bsum_et, NT);
    scan_phase1<<<nbE, 256, 0, stream>>>(deg_te, off_te, bsum_te, NE);
    scan_phase2<<<1, 256, 0, stream>>>(bsum_ee, nbE);
    scan_phase2<<<1, 256, 0, stream>>>(bsum_et, nbT);
    scan_phase2<<<1, 256, 0, stream>>>(bsum_te, nbE);
    scan_phase3<<<(NE + 255) / 256, 256, 0, stream>>>(off_ee, cur_ee, bsum_ee, NE);
    scan_phase3<<<(NT + 255) / 256, 256, 0, stream>>>(off_et, cur_et, bsum_et, NT);
    scan_phase3<<<(NE + 255) / 256, 256, 0, stream>>>(off_te, cur_te, bsum_te, NE);
    fill_adj<<<(EE + 255) / 256, 256, 0, stream>>>(e2e_src, e2e_dst, cur_ee, adj_ee, EE);
    fill_adj<<<(ET + 255) / 256, 256, 0, stream>>>(e2t_src, e2t_dst, cur_et, adj_et, ET);
    fill_adj<<<(TE + 255) / 256, 256, 0, stream>>>(t2e_src, t2e_dst, cur_te, adj_te, TE);

    // ---- layers ----
    for (int l = 0; l < NLAY; ++l) {
        const bf16* wl_ev = wbuf + (size_t)l * 10 * D * D;   // mats 0..2 (slots 0-5)
        const bf16* wl_tr = wl_ev + (size_t)6 * D * D;       // mats 3..4 (slots 6-9)
        const float* be = bbuf + (size_t)l * 2 * D;
        const float* bt = be + D;

        agg_mean_bf16<<<(NE + 15) / 16, 256, 0, stream>>>(x_event, off_ee, adj_ee, m_ee, NE);
        agg_mean_bf16<<<(NE + 15) / 16, 256, 0, stream>>>(x_trace, off_te, adj_te, m_te, NE);
        agg_mean_bf16<<<(NT + 15) / 16, 256, 0, stream>>>(x_event, off_et, adj_et, m_et, NT);

        gemm_fused<3><<<(NE + 127) / 128, 256, 0, stream>>>(m_ee, m_te, x_event, wl_ev, be, nx_event, NE);
        gemm_fused<2><<<(NT + 127) / 128, 256, 0, stream>>>(m_et, x_trace, (const bf16*)nullptr, wl_tr, bt, nx_trace, NT);

        bf16* t;
        t = x_event; x_event = nx_event; nx_event = t;
        t = x_trace; x_trace = nx_trace; nx_trace = t;
    }

    // ---- pooling ----
    hipMemsetAsync(pooled, 0, (size_t)NB * D * 4, stream);
    const int CHUNK = 64;
    pool_bf16<<<(NE + CHUNK - 1) / CHUNK, D, 0, stream>>>(x_event, event_batch, pooled, NE, CHUNK);
    pool_bf16<<<(NT + CHUNK - 1) / CHUNK, D, 0, stream>>>(x_trace, trace_batch, pooled, NT, CHUNK);

    // ---- head ----
    head_kernel<<<NB, D, 0, stream>>>(pooled, W1, b1, W2, b2, (float*)d_out);
}